// Round 2
// baseline (308.223 us; speedup 1.0000x reference)
//
#include <hip/hip_runtime.h>

#define N_FEAT 784
#define NF4    196          // N_FEAT / 4
#define N_CLS  10

// Folded network: logits = x @ Weff^T + beff; out = softmax(logits).
// Weff/beff recomputed per block into LDS (inputs L2/L3-hot).
// 512-thread blocks (8 waves): 4 blocks/CU co-resident by LDS (126 KB),
// __launch_bounds__(512,8) caps VGPR at 64 -> 32 waves/CU (8/SIMD).
// Occupancy (TLP) does the latency hiding, so the main loop stays lean:
// 2 rows per 16-lane group, 20 accumulators, no manual unroll.
__global__ __launch_bounds__(512, 8) void sparse_fused_kernel(
    const float* __restrict__ x,
    const float* __restrict__ Wsp,   // [784,2]
    const float* __restrict__ bsp,   // [784,2]
    const float* __restrict__ fcw,   // [10,784]
    const float* __restrict__ fcb,   // [10]
    float* __restrict__ out)         // [65536,10]
{
    __shared__ float Wl[N_CLS * N_FEAT];   // folded weights, [10][784]
    __shared__ float bl[N_CLS];            // folded bias
    __shared__ float bred[8][N_CLS];

    const int tid  = threadIdx.x;
    const int lane = tid & 63;
    const int wave = tid >> 6;

    // ---- per-block fold of the sparse layer into fc ----
    float bacc[N_CLS];
#pragma unroll
    for (int n = 0; n < N_CLS; ++n) bacc[n] = 0.f;

    for (int i = tid; i < N_FEAT; i += 512) {
        // scatter map from the reference (incl. the i==782 wraparound bug)
        int c0 = (i == 782) ? 0 : i;
        int c1 = (i == 782) ? 1 : ((i == 783) ? 0 : (i + 1));
        float w0 = Wsp[2 * i], w1 = Wsp[2 * i + 1];
        float b0 = bsp[2 * i], b1 = bsp[2 * i + 1];
#pragma unroll
        for (int n = 0; n < N_CLS; ++n) {
            float f0 = fcw[n * N_FEAT + c0];
            float f1 = fcw[n * N_FEAT + c1];
            Wl[n * N_FEAT + i] = f0 * w0 + f1 * w1;
            bacc[n] += f0 * b0 + f1 * b1;
        }
    }
#pragma unroll
    for (int n = 0; n < N_CLS; ++n) {
#pragma unroll
        for (int d = 1; d < 64; d <<= 1)
            bacc[n] += __shfl_xor(bacc[n], d, 64);
    }
    if (lane == 0) {
#pragma unroll
        for (int n = 0; n < N_CLS; ++n) bred[wave][n] = bacc[n];
    }
    __syncthreads();
    if (tid < N_CLS) {
        float s = fcb[tid];
#pragma unroll
        for (int w = 0; w < 8; ++w) s += bred[w][tid];
        bl[tid] = s;
    }
    __syncthreads();

    // ---- main GEMM + softmax ----
    const float4* Wl4 = (const float4*)Wl;
    const int g  = lane >> 4;               // 16-lane group, 0..3
    const int sl = lane & 15;

    // block covers 64 rows; wave covers 8; group g owns rows rbase, rbase+1
    const int rbase = blockIdx.x * 64 + wave * 8 + g * 2;
    const float4* xr = (const float4*)(x + (size_t)rbase * N_FEAT);

    float acc0[N_CLS], acc1[N_CLS];
#pragma unroll
    for (int n = 0; n < N_CLS; ++n) { acc0[n] = 0.f; acc1[n] = 0.f; }

    // lanes stride the 196 float4 features; 12 full steps + tail (sl<4)
    for (int i = 0; i < 12; ++i) {
        const int k4 = sl + 16 * i;
        float4 x0 = xr[k4];
        float4 x1 = xr[NF4 + k4];       // row rbase+1, offset fits imm
#pragma unroll
        for (int n = 0; n < N_CLS; ++n) {
            float4 wv = Wl4[n * NF4 + k4];
            acc0[n] += wv.x * x0.x + wv.y * x0.y + wv.z * x0.z + wv.w * x0.w;
            acc1[n] += wv.x * x1.x + wv.y * x1.y + wv.z * x1.z + wv.w * x1.w;
        }
    }
    if (sl < 4) {                       // k4 = 192..195
        const int k4 = 192 + sl;
        float4 x0 = xr[k4];
        float4 x1 = xr[NF4 + k4];
#pragma unroll
        for (int n = 0; n < N_CLS; ++n) {
            float4 wv = Wl4[n * NF4 + k4];
            acc0[n] += wv.x * x0.x + wv.y * x0.y + wv.z * x0.z + wv.w * x0.w;
            acc1[n] += wv.x * x1.x + wv.y * x1.y + wv.z * x1.z + wv.w * x1.w;
        }
    }

    // intra-group (16-lane) butterfly; all 4 groups reduce in parallel
#pragma unroll
    for (int d = 1; d < 16; d <<= 1) {
#pragma unroll
        for (int n = 0; n < N_CLS; ++n) {
            acc0[n] += __shfl_xor(acc0[n], d, 64);
            acc1[n] += __shfl_xor(acc1[n], d, 64);
        }
    }

    // fused softmax for both rows (computed redundantly in all 16 lanes)
    float m0 = -1e30f, m1 = -1e30f;
#pragma unroll
    for (int n = 0; n < N_CLS; ++n) {
        acc0[n] += bl[n];
        acc1[n] += bl[n];
        m0 = fmaxf(m0, acc0[n]);
        m1 = fmaxf(m1, acc1[n]);
    }
    float den0 = 0.f, den1 = 0.f;
#pragma unroll
    for (int n = 0; n < N_CLS; ++n) {
        acc0[n] = __expf(acc0[n] - m0);
        acc1[n] = __expf(acc1[n] - m1);
        den0 += acc0[n];
        den1 += acc1[n];
    }
    float inv0 = 1.0f / den0, inv1 = 1.0f / den1;
    float v0 = acc0[0], v1 = acc1[0];
#pragma unroll
    for (int n = 1; n < N_CLS; ++n) {
        v0 = (sl == n) ? acc0[n] : v0;
        v1 = (sl == n) ? acc1[n] : v1;
    }
    if (sl < N_CLS) {
        out[(size_t)rbase * N_CLS + sl]       = v0 * inv0;
        out[(size_t)(rbase + 1) * N_CLS + sl] = v1 * inv1;
    }
}

extern "C" void kernel_launch(void* const* d_in, const int* in_sizes, int n_in,
                              void* d_out, int out_size, void* d_ws, size_t ws_size,
                              hipStream_t stream) {
    const float* x   = (const float*)d_in[0];   // [65536,784]
    const float* Wsp = (const float*)d_in[1];   // [784,2]
    const float* bsp = (const float*)d_in[2];   // [784,2]
    const float* fcw = (const float*)d_in[3];   // [10,784]
    const float* fcb = (const float*)d_in[4];   // [10]
    float* out = (float*)d_out;                 // [65536,10]

    // 1024 blocks x 512 threads: 8 waves/block, 64 rows/block,
    // 4 blocks/CU co-resident (126 KB LDS), target 32 waves/CU
    sparse_fused_kernel<<<1024, 512, 0, stream>>>(x, Wsp, bsp, fcw, fcb, out);
}

// Round 3
// 294.181 us; speedup vs baseline: 1.0477x; 1.0477x over previous
//
#include <hip/hip_runtime.h>

#define N_FEAT 784
#define NF4    196          // N_FEAT / 4
#define N_CLS  10

// Folded network: logits = x @ Weff^T + beff; out = softmax(logits).
// Weff/beff recomputed per block into LDS (inputs L2/L3-hot).
// R0 structure (best known): 256 thr, 16-lane group owns 2 rows, 2 passes.
// New: 1-deep register prefetch of the next iteration's x loads so each
// wave keeps 2KB in flight during the 80-FMA block (latency hiding by MLP),
// plus cross-pass prefetch so loads fly during reduction/softmax/store.
__global__ __launch_bounds__(256, 4) void sparse_fused_kernel(
    const float* __restrict__ x,
    const float* __restrict__ Wsp,   // [784,2]
    const float* __restrict__ bsp,   // [784,2]
    const float* __restrict__ fcw,   // [10,784]
    const float* __restrict__ fcb,   // [10]
    float* __restrict__ out)         // [65536,10]
{
    __shared__ float Wl[N_CLS * N_FEAT];   // folded weights, [10][784]
    __shared__ float bl[N_CLS];            // folded bias
    __shared__ float bred[4][N_CLS];

    const int tid  = threadIdx.x;
    const int lane = tid & 63;
    const int wave = tid >> 6;

    // ---- per-block fold of the sparse layer into fc ----
    float bacc[N_CLS];
#pragma unroll
    for (int n = 0; n < N_CLS; ++n) bacc[n] = 0.f;

    for (int i = tid; i < N_FEAT; i += 256) {
        // scatter map from the reference (incl. the i==782 wraparound bug)
        int c0 = (i == 782) ? 0 : i;
        int c1 = (i == 782) ? 1 : ((i == 783) ? 0 : (i + 1));
        float w0 = Wsp[2 * i], w1 = Wsp[2 * i + 1];
        float b0 = bsp[2 * i], b1 = bsp[2 * i + 1];
#pragma unroll
        for (int n = 0; n < N_CLS; ++n) {
            float f0 = fcw[n * N_FEAT + c0];
            float f1 = fcw[n * N_FEAT + c1];
            Wl[n * N_FEAT + i] = f0 * w0 + f1 * w1;
            bacc[n] += f0 * b0 + f1 * b1;
        }
    }
#pragma unroll
    for (int n = 0; n < N_CLS; ++n) {
#pragma unroll
        for (int d = 1; d < 64; d <<= 1)
            bacc[n] += __shfl_xor(bacc[n], d, 64);
    }
    if (lane == 0) {
#pragma unroll
        for (int n = 0; n < N_CLS; ++n) bred[wave][n] = bacc[n];
    }
    __syncthreads();
    if (tid < N_CLS)
        bl[tid] = bred[0][tid] + bred[1][tid] + bred[2][tid] + bred[3][tid] + fcb[tid];
    __syncthreads();

    // ---- main GEMM + softmax ----
    const float4* Wl4 = (const float4*)Wl;
    const int gw = blockIdx.x * 4 + wave;   // global wave id, 0..4095
    const int g  = lane >> 4;               // 16-lane group, 0..3
    const int sl = lane & 15;

    const int rb0 = (gw * 2 + 0) * 8 + g * 2;
    const int rb1 = (gw * 2 + 1) * 8 + g * 2;
    const float4* xa = (const float4*)(x + (size_t)rb0 * N_FEAT);
    const float4* xb = (const float4*)(x + (size_t)rb1 * N_FEAT);

    // tail prefetch index: k4=192..195 for sl<4; clamped in-bounds dummy else
    const int tk4 = (sl < 4) ? (192 + sl) : sl;

    float acc0[N_CLS], acc1[N_CLS];
#pragma unroll
    for (int n = 0; n < N_CLS; ++n) { acc0[n] = 0.f; acc1[n] = 0.f; }

    // ================= pass 0 =================
    float4 cx0 = xa[sl];
    float4 cx1 = xa[NF4 + sl];

    for (int i = 0; i < 12; ++i) {
        const int nk4 = (i < 11) ? (sl + 16 * (i + 1)) : tk4;
        float4 nx0 = xa[nk4];              // prefetch next iter (in flight
        float4 nx1 = xa[NF4 + nk4];        //  during the FMA block below)
        const int k4 = sl + 16 * i;
#pragma unroll
        for (int n = 0; n < N_CLS; ++n) {
            float4 wv = Wl4[n * NF4 + k4];
            acc0[n] += wv.x * cx0.x + wv.y * cx0.y + wv.z * cx0.z + wv.w * cx0.w;
            acc1[n] += wv.x * cx1.x + wv.y * cx1.y + wv.z * cx1.z + wv.w * cx1.w;
        }
        cx0 = nx0; cx1 = nx1;
    }

    // prefetch pass-1 head now: loads fly during tail + reduction + softmax
    float4 h0 = xb[sl];
    float4 h1 = xb[NF4 + sl];

    if (sl < 4) {                          // tail k4 = 192..195
        const int k4 = 192 + sl;
#pragma unroll
        for (int n = 0; n < N_CLS; ++n) {
            float4 wv = Wl4[n * NF4 + k4];
            acc0[n] += wv.x * cx0.x + wv.y * cx0.y + wv.z * cx0.z + wv.w * cx0.w;
            acc1[n] += wv.x * cx1.x + wv.y * cx1.y + wv.z * cx1.z + wv.w * cx1.w;
        }
    }

#pragma unroll
    for (int d = 1; d < 16; d <<= 1) {
#pragma unroll
        for (int n = 0; n < N_CLS; ++n) {
            acc0[n] += __shfl_xor(acc0[n], d, 64);
            acc1[n] += __shfl_xor(acc1[n], d, 64);
        }
    }
    {
        float m0 = -1e30f, m1 = -1e30f;
#pragma unroll
        for (int n = 0; n < N_CLS; ++n) {
            acc0[n] += bl[n];
            acc1[n] += bl[n];
            m0 = fmaxf(m0, acc0[n]);
            m1 = fmaxf(m1, acc1[n]);
        }
        float den0 = 0.f, den1 = 0.f;
#pragma unroll
        for (int n = 0; n < N_CLS; ++n) {
            acc0[n] = __expf(acc0[n] - m0);
            acc1[n] = __expf(acc1[n] - m1);
            den0 += acc0[n];
            den1 += acc1[n];
        }
        float inv0 = 1.0f / den0, inv1 = 1.0f / den1;
        float v0 = acc0[0], v1 = acc1[0];
#pragma unroll
        for (int n = 1; n < N_CLS; ++n) {
            v0 = (sl == n) ? acc0[n] : v0;
            v1 = (sl == n) ? acc1[n] : v1;
        }
        if (sl < N_CLS) {
            out[(size_t)rb0 * N_CLS + sl]       = v0 * inv0;
            out[(size_t)(rb0 + 1) * N_CLS + sl] = v1 * inv1;
        }
    }

    // ================= pass 1 =================
#pragma unroll
    for (int n = 0; n < N_CLS; ++n) { acc0[n] = 0.f; acc1[n] = 0.f; }
    cx0 = h0; cx1 = h1;

    for (int i = 0; i < 12; ++i) {
        const int nk4 = (i < 11) ? (sl + 16 * (i + 1)) : tk4;
        float4 nx0 = xb[nk4];
        float4 nx1 = xb[NF4 + nk4];
        const int k4 = sl + 16 * i;
#pragma unroll
        for (int n = 0; n < N_CLS; ++n) {
            float4 wv = Wl4[n * NF4 + k4];
            acc0[n] += wv.x * cx0.x + wv.y * cx0.y + wv.z * cx0.z + wv.w * cx0.w;
            acc1[n] += wv.x * cx1.x + wv.y * cx1.y + wv.z * cx1.z + wv.w * cx1.w;
        }
        cx0 = nx0; cx1 = nx1;
    }

    if (sl < 4) {
        const int k4 = 192 + sl;
#pragma unroll
        for (int n = 0; n < N_CLS; ++n) {
            float4 wv = Wl4[n * NF4 + k4];
            acc0[n] += wv.x * cx0.x + wv.y * cx0.y + wv.z * cx0.z + wv.w * cx0.w;
            acc1[n] += wv.x * cx1.x + wv.y * cx1.y + wv.z * cx1.z + wv.w * cx1.w;
        }
    }

#pragma unroll
    for (int d = 1; d < 16; d <<= 1) {
#pragma unroll
        for (int n = 0; n < N_CLS; ++n) {
            acc0[n] += __shfl_xor(acc0[n], d, 64);
            acc1[n] += __shfl_xor(acc1[n], d, 64);
        }
    }
    {
        float m0 = -1e30f, m1 = -1e30f;
#pragma unroll
        for (int n = 0; n < N_CLS; ++n) {
            acc0[n] += bl[n];
            acc1[n] += bl[n];
            m0 = fmaxf(m0, acc0[n]);
            m1 = fmaxf(m1, acc1[n]);
        }
        float den0 = 0.f, den1 = 0.f;
#pragma unroll
        for (int n = 0; n < N_CLS; ++n) {
            acc0[n] = __expf(acc0[n] - m0);
            acc1[n] = __expf(acc1[n] - m1);
            den0 += acc0[n];
            den1 += acc1[n];
        }
        float inv0 = 1.0f / den0, inv1 = 1.0f / den1;
        float v0 = acc0[0], v1 = acc1[0];
#pragma unroll
        for (int n = 1; n < N_CLS; ++n) {
            v0 = (sl == n) ? acc0[n] : v0;
            v1 = (sl == n) ? acc1[n] : v1;
        }
        if (sl < N_CLS) {
            out[(size_t)rb1 * N_CLS + sl]       = v0 * inv0;
            out[(size_t)(rb1 + 1) * N_CLS + sl] = v1 * inv1;
        }
    }
}

extern "C" void kernel_launch(void* const* d_in, const int* in_sizes, int n_in,
                              void* d_out, int out_size, void* d_ws, size_t ws_size,
                              hipStream_t stream) {
    const float* x   = (const float*)d_in[0];   // [65536,784]
    const float* Wsp = (const float*)d_in[1];   // [784,2]
    const float* bsp = (const float*)d_in[2];   // [784,2]
    const float* fcw = (const float*)d_in[3];   // [10,784]
    const float* fcb = (const float*)d_in[4];   // [10]
    float* out = (float*)d_out;                 // [65536,10]

    // 1024 blocks x 256 threads: 4 waves/block, 2 passes x 8 rows per wave
    sparse_fused_kernel<<<1024, 256, 0, stream>>>(x, Wsp, bsp, fcw, fcb, out);
}